// Round 2
// baseline (210.500 us; speedup 1.0000x reference)
//
#include <hip/hip_runtime.h>
#include <stdint.h>

typedef unsigned short u16;
typedef __bf16 bf16x8 __attribute__((ext_vector_type(8)));
typedef float f32x4 __attribute__((ext_vector_type(4)));

static constexpr int kDim   = 1024;
static constexpr int kHeads = 16;
static constexpr int kN     = 2048;   // sequence length (power of two!)
static constexpr int kB     = 2;
static constexpr int kTok   = 4096;   // kB * kN

// ---------------- workspace byte offsets ----------------
static constexpr size_t OFF_XB   = 0;                                   // x in bf16      [4096][1024]
static constexpr size_t OFF_VT   = OFF_XB   + (size_t)kTok*kDim*2;      // v^T bf16       [b*1024+c][2048]
static constexpr size_t OFF_OC   = OFF_VT   + (size_t)kTok*kDim*2;      // conv out bf16  [4096][1024]
static constexpr size_t OFF_WVB  = OFF_OC   + (size_t)kTok*kDim*2;      // wv bf16
static constexpr size_t OFF_WPB  = OFF_WVB  + (size_t)kDim*kDim*2;      // wp bf16
static constexpr size_t OFF_XSUM = OFF_WPB  + (size_t)kDim*kDim*2;      // [2][1024] f32
static constexpr size_t OFF_KAVG = OFF_XSUM + (size_t)kB*kDim*4;        // [2][16][64] f32
static constexpr size_t OFF_WZ   = OFF_KAVG + (size_t)kB*kHeads*64*4;   // [32][1024] f32
static constexpr size_t OFF_Z    = OFF_WZ   + (size_t)kB*kHeads*kDim*4; // [32][2048] f32
static constexpr size_t OFF_ATTN = OFF_Z    + (size_t)kB*kHeads*kN*4;   // [32][2064] bf16 (2056 used)
static constexpr int kAttnStride = 2064;   // u16 elements per attn row (16B multiple)

// ---------------- helpers ----------------
__device__ __forceinline__ u16 f2bf(float f) {
  unsigned int u = __builtin_bit_cast(unsigned int, f);
  u = (u + 0x7FFFu + ((u >> 16) & 1u)) >> 16;   // RNE
  return (u16)u;
}

// async global->LDS, 16B per lane; LDS dest is wave-uniform base + lane*16
__device__ __forceinline__ void gload_lds16(const void* g, void* l) {
  __builtin_amdgcn_global_load_lds(
      (const __attribute__((address_space(1))) unsigned int*)g,
      (__attribute__((address_space(3))) unsigned int*)l, 16, 0, 0);
}

// ---------------- tiny f32 kernels ----------------
__global__ void cvt_bf16_kernel(const float* __restrict__ in, u16* __restrict__ out, int n4) {
  int i = blockIdx.x * 256 + threadIdx.x;
  if (i < n4) {
    float4 f = reinterpret_cast<const float4*>(in)[i];
    u16 a = f2bf(f.x), b = f2bf(f.y), c = f2bf(f.z), d = f2bf(f.w);
    unsigned int lo = (unsigned int)a | ((unsigned int)b << 16);
    unsigned int hi = (unsigned int)c | ((unsigned int)d << 16);
    reinterpret_cast<uint2*>(out)[i] = make_uint2(lo, hi);
  }
}

// column sums of x over the sequence axis (atomicAdd into zeroed buffer)
__global__ void xsum_kernel(const float* __restrict__ x, float* __restrict__ xsum) {
  int bid = blockIdx.x;            // 128 blocks: b(2) x nc(16) x cc(4)
  int cc = bid & 3, nc = (bid >> 2) & 15, b = bid >> 6;
  int c = cc * 256 + threadIdx.x;
  const float* xp = x + ((size_t)b * kN + nc * 128) * kDim + c;
  float s = 0.f;
  for (int n = 0; n < 128; ++n) s += xp[(size_t)n * kDim];
  atomicAdd(&xsum[b * kDim + c], s);
}

// k_avg[b,h,d] = (1/N) * xsum[b,:] . wk[h*64+d,:]
__global__ void kavg_kernel(const float* __restrict__ xsum, const float* __restrict__ wk,
                            float* __restrict__ kavg) {
  int o = blockIdx.x;              // [0,2048) = b*1024 + h*64 + d
  int b = o >> 10;
  int lane = threadIdx.x;          // 64 threads
  const float* wkr = wk + (size_t)(o & 1023) * kDim;
  const float* xs = xsum + b * kDim;
  float s = 0.f;
  for (int k = lane; k < kDim; k += 64) s += xs[k] * wkr[k];
#pragma unroll
  for (int off = 32; off; off >>= 1) s += __shfl_xor(s, off);
  if (lane == 0) kavg[o] = s * (1.0f / (float)kN);
}

// wz[b,h,c] = scale * sum_d kavg[b,h,d] * wq[h*64+d, c]
__global__ void wz_kernel(const float* __restrict__ kavg, const float* __restrict__ wq,
                          float* __restrict__ wz) {
  int bh = blockIdx.x;             // 32 blocks
  int h = bh & 15, tid = threadIdx.x;
  __shared__ float kl[64];
  if (tid < 64) kl[tid] = kavg[bh * 64 + tid];
  __syncthreads();
  float a0 = 0.f, a1 = 0.f, a2 = 0.f, a3 = 0.f;
  const float* wqb = wq + (size_t)h * 64 * kDim + tid;
  for (int d = 0; d < 64; ++d) {
    float kd = kl[d];
    const float* r = wqb + (size_t)d * kDim;
    a0 += kd * r[0]; a1 += kd * r[256]; a2 += kd * r[512]; a3 += kd * r[768];
  }
  const float scale = 0.125f;      // 64^-0.5
  float* o = wz + (size_t)bh * kDim + tid;
  o[0] = a0 * scale; o[256] = a1 * scale; o[512] = a2 * scale; o[768] = a3 * scale;
}

// z[b,h,n] = x[b,n,:] . wz[b,h,:]
__global__ void z_kernel(const float* __restrict__ x, const float* __restrict__ wz,
                         float* __restrict__ z) {
  int blk = blockIdx.x;            // 4096 = b*2048 + n
  int b = blk >> 11, n = blk & 2047;
  __shared__ float xr[kDim];
  int tid = threadIdx.x, wid = tid >> 6, lane = tid & 63;
  reinterpret_cast<float4*>(xr)[tid] = reinterpret_cast<const float4*>(x + (size_t)blk * kDim)[tid];
  __syncthreads();
#pragma unroll
  for (int hh = 0; hh < 4; ++hh) {
    int h = wid * 4 + hh;
    const float* wzr = wz + (size_t)(b * kHeads + h) * kDim;
    float s = 0.f;
    for (int k = lane; k < kDim; k += 64) s += xr[k] * wzr[k];
#pragma unroll
    for (int off = 32; off; off >>= 1) s += __shfl_xor(s, off);
    if (lane == 0) z[(size_t)(b * kHeads + h) * kN + n] = s;
  }
}

// row softmax (32 rows x 2048) -> bf16, with 8-element circular tail (row length 2056)
__global__ void softmax_kernel(const float* __restrict__ z, u16* __restrict__ attn2) {
  int row = blockIdx.x, tid = threadIdx.x;
  int lane = tid & 63, wid = tid >> 6;
  const float* zr = z + (size_t)row * kN;
  float v[8];
  float mx = -1e30f;
#pragma unroll
  for (int j = 0; j < 8; ++j) { v[j] = zr[tid + j * 256]; mx = fmaxf(mx, v[j]); }
#pragma unroll
  for (int off = 32; off; off >>= 1) mx = fmaxf(mx, __shfl_xor(mx, off));
  __shared__ float redm[4], reds[4];
  if (lane == 0) redm[wid] = mx;
  __syncthreads();
  mx = fmaxf(fmaxf(redm[0], redm[1]), fmaxf(redm[2], redm[3]));
  float s = 0.f;
#pragma unroll
  for (int j = 0; j < 8; ++j) { v[j] = __expf(v[j] - mx); s += v[j]; }
#pragma unroll
  for (int off = 32; off; off >>= 1) s += __shfl_xor(s, off);
  if (lane == 0) reds[wid] = s;
  __syncthreads();
  s = reds[0] + reds[1] + reds[2] + reds[3];
  float inv = 1.0f / s;
  u16* out = attn2 + (size_t)row * kAttnStride;
#pragma unroll
  for (int j = 0; j < 8; ++j) out[tid + j * 256] = f2bf(v[j] * inv);
  if (tid < 8) out[2048 + tid] = f2bf(v[0] * inv);   // thread tid holds t=tid (j=0)
}

// ---------------- bt-GEMM: C[m,n] = sum_k A[m,k]*B[n,k] ----------------
// BM=128, BN=64, BK=64, 256 threads (4 waves, 2x2), wave tile 64x32 (4x2 frags).
// MODE 0: write bf16 TRANSPOSED into vT[(b*1024+n)*2048 + (m&2047)]   (V-GEMM)
// MODE 1: write f32 + bias into y[m*1024+n]                            (projection)
template <int MODE>
__global__ __launch_bounds__(256, 2)
void gemm_bt_kernel(const u16* __restrict__ A, const u16* __restrict__ B,
                    void* __restrict__ Cout, const float* __restrict__ bias, int K) {
  __shared__ __align__(16) u16 As[128 * 64];
  __shared__ __align__(16) u16 Bs[64 * 64];
  int tid = threadIdx.x, lane = tid & 63, wid = tid >> 6;
  int wm = wid >> 1, wn = wid & 1;
  int lrow = lane & 15, kg = lane >> 4;
  int m0 = blockIdx.y * 128, n0 = blockIdx.x * 64;

  f32x4 acc[4][2];
#pragma unroll
  for (int i = 0; i < 4; ++i)
#pragma unroll
    for (int j = 0; j < 2; ++j) acc[i][j] = (f32x4){0.f, 0.f, 0.f, 0.f};

  for (int k0 = 0; k0 < K; k0 += 64) {
    // stage A tile [128][64] (1024 x 16B chunks, XOR-(row&7) chunk swizzle on source)
#pragma unroll
    for (int it = 0; it < 4; ++it) {
      int bchunk = it * 256 + wid * 64;
      int chunk = bchunk + lane;
      int row = chunk >> 3, cb = chunk & 7;
      int cs = cb ^ (row & 7);
      gload_lds16(A + (size_t)(m0 + row) * K + k0 + cs * 8, &As[bchunk * 8]);
    }
    // stage B tile [64][64]
#pragma unroll
    for (int it = 0; it < 2; ++it) {
      int bchunk = it * 256 + wid * 64;
      int chunk = bchunk + lane;
      int row = chunk >> 3, cb = chunk & 7;
      int cs = cb ^ (row & 7);
      gload_lds16(B + (size_t)(n0 + row) * K + k0 + cs * 8, &Bs[bchunk * 8]);
    }
    __syncthreads();
#pragma unroll
    for (int ks = 0; ks < 2; ++ks) {
      bf16x8 af[4], bfv[2];
#pragma unroll
      for (int mf = 0; mf < 4; ++mf) {
        int r = wm * 64 + mf * 16 + lrow;
        int c = (ks * 4 + kg) ^ (r & 7);
        af[mf] = *reinterpret_cast<const bf16x8*>(&As[r * 64 + c * 8]);
      }
#pragma unroll
      for (int nf = 0; nf < 2; ++nf) {
        int r = wn * 32 + nf * 16 + lrow;
        int c = (ks * 4 + kg) ^ (r & 7);
        bfv[nf] = *reinterpret_cast<const bf16x8*>(&Bs[r * 64 + c * 8]);
      }
#pragma unroll
      for (int mf = 0; mf < 4; ++mf)
#pragma unroll
        for (int nf = 0; nf < 2; ++nf)
          acc[mf][nf] = __builtin_amdgcn_mfma_f32_16x16x32_bf16(af[mf], bfv[nf], acc[mf][nf], 0, 0, 0);
    }
    __syncthreads();
  }

  if (MODE == 0) {
    u16* vT = (u16*)Cout;
#pragma unroll
    for (int mf = 0; mf < 4; ++mf) {
      int row0 = m0 + wm * 64 + mf * 16 + kg * 4;   // token index; 4 consecutive
      int bb = row0 >> 11, u = row0 & 2047;
#pragma unroll
      for (int nf = 0; nf < 2; ++nf) {
        int col = n0 + wn * 32 + nf * 16 + lrow;    // channel
        f32x4 a = acc[mf][nf];
        unsigned int lo = (unsigned int)f2bf(a.x) | ((unsigned int)f2bf(a.y) << 16);
        unsigned int hi = (unsigned int)f2bf(a.z) | ((unsigned int)f2bf(a.w) << 16);
        *reinterpret_cast<uint2*>(&vT[((size_t)(bb * kDim + col)) * kN + u]) = make_uint2(lo, hi);
      }
    }
  } else {
    float* y = (float*)Cout;
#pragma unroll
    for (int nf = 0; nf < 2; ++nf) {
      int col = n0 + wn * 32 + nf * 16 + lrow;
      float bv = bias[col];
#pragma unroll
      for (int mf = 0; mf < 4; ++mf) {
        int row0 = m0 + wm * 64 + mf * 16 + kg * 4;
        f32x4 a = acc[mf][nf];
        y[(size_t)(row0 + 0) * kDim + col] = a.x + bv;
        y[(size_t)(row0 + 1) * kDim + col] = a.y + bv;
        y[(size_t)(row0 + 2) * kDim + col] = a.z + bv;
        y[(size_t)(row0 + 3) * kDim + col] = a.w + bv;
      }
    }
  }
}

// ---------------- circular-conv GEMM ----------------
// outT[d,i] = sum_u vT[d,u] * attn[(u-i) & 2047], per (b,h).
// Block: 256 thr (2x2 waves), tile = 64(d) x 128(i), K-loop over u (BK=64).
// Circulant B-fragments are gathered 16B-aligned from 8 shift-replicated LDS copies of attn.
__global__ __launch_bounds__(256, 2)
void conv_kernel(const u16* __restrict__ vT, const u16* __restrict__ attn2,
                 u16* __restrict__ oc) {
  static constexpr int RS = 2056;               // rep stride (u16); 2056*2 bytes = 16B multiple
  __shared__ __align__(16) u16 reps[8 * RS];
  __shared__ __align__(16) u16 vts[64 * 64];
  int tid = threadIdx.x, lane = tid & 63, wid = tid >> 6;
  int wm = wid >> 1, wn = wid & 1;
  int lrow = lane & 15, kg = lane >> 4;
  int i0 = blockIdx.x * 128;
  int bh = blockIdx.y;                          // b*16 + h
  int b = bh >> 4, h = bh & 15;

  // stage 8 shifted replicas: reps[p][m] = attn_row[m+p]
  const u16* arow = attn2 + (size_t)bh * kAttnStride;
  for (int p = 0; p < 8; ++p)
    for (int j = tid; j < 2048; j += 256) reps[p * RS + j] = arow[j + p];

  f32x4 acc[2][4];
#pragma unroll
  for (int i = 0; i < 2; ++i)
#pragma unroll
    for (int j = 0; j < 4; ++j) acc[i][j] = (f32x4){0.f, 0.f, 0.f, 0.f};

  for (int u0 = 0; u0 < kN; u0 += 64) {
    // stage vT tile [64 d][64 u]
#pragma unroll
    for (int it = 0; it < 2; ++it) {
      int bchunk = it * 256 + wid * 64;
      int chunk = bchunk + lane;
      int d = chunk >> 3, cb = chunk & 7;
      int cs = cb ^ (d & 7);
      gload_lds16(vT + (size_t)(bh * 64 + d) * kN + u0 + cs * 8, &vts[bchunk * 8]);
    }
    __syncthreads();                            // also covers reps on first iteration
#pragma unroll
    for (int ks = 0; ks < 2; ++ks) {
      bf16x8 af[2], bfv[4];
#pragma unroll
      for (int mf = 0; mf < 2; ++mf) {
        int r = wm * 32 + mf * 16 + lrow;
        int c = (ks * 4 + kg) ^ (r & 7);
        af[mf] = *reinterpret_cast<const bf16x8*>(&vts[r * 64 + c * 8]);
      }
#pragma unroll
      for (int nf = 0; nf < 4; ++nf) {
        int i = i0 + wn * 64 + nf * 16 + lrow;
        int s = (u0 + ks * 32 + kg * 8 - i) & 2047;
        int p = s & 7;
        bfv[nf] = *reinterpret_cast<const bf16x8*>(&reps[p * RS + (s & ~7)]);
      }
#pragma unroll
      for (int mf = 0; mf < 2; ++mf)
#pragma unroll
        for (int nf = 0; nf < 4; ++nf)
          acc[mf][nf] = __builtin_amdgcn_mfma_f32_16x16x32_bf16(af[mf], bfv[nf], acc[mf][nf], 0, 0, 0);
    }
    __syncthreads();
  }

  // store: oc[(b*2048 + i)*1024 + h*64 + d], 4 consecutive d per lane -> 8B store
#pragma unroll
  for (int mf = 0; mf < 2; ++mf) {
    int d = wm * 32 + mf * 16 + kg * 4;
#pragma unroll
    for (int nf = 0; nf < 4; ++nf) {
      int i = i0 + wn * 64 + nf * 16 + lrow;
      f32x4 a = acc[mf][nf];
      unsigned int lo = (unsigned int)f2bf(a.x) | ((unsigned int)f2bf(a.y) << 16);
      unsigned int hi = (unsigned int)f2bf(a.z) | ((unsigned int)f2bf(a.w) << 16);
      *reinterpret_cast<uint2*>(&oc[((size_t)(b * kN + i)) * kDim + h * 64 + d]) = make_uint2(lo, hi);
    }
  }
}

// ---------------- launch ----------------
extern "C" void kernel_launch(void* const* d_in, const int* in_sizes, int n_in,
                              void* d_out, int out_size, void* d_ws, size_t ws_size,
                              hipStream_t stream) {
  const float* x  = (const float*)d_in[0];
  const float* wq = (const float*)d_in[1];
  const float* wk = (const float*)d_in[2];
  const float* wv = (const float*)d_in[3];
  const float* wp = (const float*)d_in[4];
  const float* bp = (const float*)d_in[5];
  char* ws = (char*)d_ws;

  u16*   xb    = (u16*)(ws + OFF_XB);
  u16*   vTb   = (u16*)(ws + OFF_VT);
  u16*   ocb   = (u16*)(ws + OFF_OC);
  u16*   wvb   = (u16*)(ws + OFF_WVB);
  u16*   wpb   = (u16*)(ws + OFF_WPB);
  float* xsum  = (float*)(ws + OFF_XSUM);
  float* kavg  = (float*)(ws + OFF_KAVG);
  float* wz    = (float*)(ws + OFF_WZ);
  float* z     = (float*)(ws + OFF_Z);
  u16*   attn2 = (u16*)(ws + OFF_ATTN);

  hipMemsetAsync(ws + OFF_XSUM, 0, (size_t)kB * kDim * 4, stream);

  cvt_bf16_kernel<<<4096, 256, 0, stream>>>(x,  xb,  kTok * kDim / 4);
  cvt_bf16_kernel<<<1024, 256, 0, stream>>>(wv, wvb, kDim * kDim / 4);
  cvt_bf16_kernel<<<1024, 256, 0, stream>>>(wp, wpb, kDim * kDim / 4);

  xsum_kernel<<<128, 256, 0, stream>>>(x, xsum);
  kavg_kernel<<<2048, 64, 0, stream>>>(xsum, wk, kavg);
  wz_kernel<<<32, 256, 0, stream>>>(kavg, wq, wz);
  z_kernel<<<4096, 256, 0, stream>>>(x, wz, z);
  softmax_kernel<<<32, 256, 0, stream>>>(z, attn2);

  // V-GEMM: v = x @ wv^T, written transposed per (b, channel) row
  gemm_bt_kernel<0><<<dim3(16, 32), 256, 0, stream>>>(xb, wvb, vTb, nullptr, kDim);
  // circular conv per (b,h)
  conv_kernel<<<dim3(16, 32), 256, 0, stream>>>(vTb, attn2, ocb);
  // projection: y = oc @ wp^T + bp (f32 out)
  gemm_bt_kernel<1><<<dim3(16, 32), 256, 0, stream>>>(ocb, wpb, (float*)d_out, bp, kDim);
}